// Round 1
// 867.771 us; speedup vs baseline: 1.0580x; 1.0580x over previous
//
#include <hip/hip_runtime.h>
#include <math.h>

#define Bsz 512
#define Dd  256
#define Hh  32
#define Ww  32
#define TEMP 0.1f
#define EPS_COS 1e-8f
#define EPS_LOG 1e-20f

__device__ __forceinline__ float waveSum(float v) {
    for (int o = 32; o; o >>= 1) v += __shfl_down(v, o);
    return v;
}
__device__ __forceinline__ float waveMax(float v) {
    for (int o = 32; o; o >>= 1) v = fmaxf(v, __shfl_down(v, o));
    return v;
}

// Kernel 1: one wave per (set, b, d).
// Lane layout for loads: r = lane>>3 (8 rows), c4 = lane&7 (float4 col group).
// One float4 load covers 8 rows x 32 cols; box height <= 14 rows -> exactly
// TWO independent loads (vs ~7 dependent scalar iterations before).
__global__ __launch_bounds__(256) void desc_kernel(
    const float* __restrict__ f1, const float* __restrict__ f2,
    const float* __restrict__ bb1, const float* __restrict__ bb2,
    float* __restrict__ d1, float* __restrict__ d2, float* __restrict__ d2t)
{
    int wid  = (blockIdx.x * 256 + threadIdx.x) >> 6;   // global wave id
    int lane = threadIdx.x & 63;
    const int total = Bsz * Dd;
    int set = (wid >= total) ? 1 : 0;
    int w   = wid - set * total;
    int b   = w >> 8;          // / Dd
    int d   = w & (Dd - 1);

    const float* __restrict__ f  = set ? f2  : f1;
    const float* __restrict__ bb = set ? bb2 : bb1;
    float4 bx = *(const float4*)(bb + b * 4);
    float x0 = bx.x, y0 = bx.y, x1 = bx.z, y1 = bx.w;

    int   cl    = lane & 31;
    float coord = ((float)cl + 0.5f) * (1.0f / 32.0f);   // exact, matches ref
    bool inY = (coord >= y0) && (coord <= y1);
    bool inX = (coord >= x0) && (coord <= x1);
    unsigned my = (unsigned)__ballot(inY);   // low 32 bits = pattern (dup'd in high)
    unsigned mx = (unsigned)__ballot(inX);
    int ny = __popc(my), nx = __popc(mx);
    float denom = fmaxf((float)(ny * nx), 1.0f);

    int iy0 = __ffs(my) - 1;       // y-mask is a contiguous interval
    int iy1 = 31 - __clz(my);      // (interval test on monotone coords)

    int r  = lane >> 3;            // 0..7
    int c4 = lane & 7;             // 0..7 -> cols 4*c4 .. 4*c4+3
    const float* base = f + (size_t)(b * Dd + d) * (Hh * Ww);
    int h0 = iy0 + r, h1 = h0 + 8;
    float4 v0 = {0.0f, 0.0f, 0.0f, 0.0f};
    float4 v1 = {0.0f, 0.0f, 0.0f, 0.0f};
    if (h0 >= 0 && h0 <= iy1) v0 = *(const float4*)(base + h0 * Ww + c4 * 4);
    if (h1 >= 0 && h1 <= iy1) v1 = *(const float4*)(base + h1 * Ww + c4 * 4);

    unsigned colbits = (mx >> (c4 * 4)) & 0xFu;   // exact x-mask from ballot
    float s = 0.0f;
    if (colbits & 1u) s += v0.x + v1.x;
    if (colbits & 2u) s += v0.y + v1.y;
    if (colbits & 4u) s += v0.z + v1.z;
    if (colbits & 8u) s += v0.w + v1.w;

    s = waveSum(s);
    if (lane == 0) {
        float v = s / denom;
        if (set) { d2[b * Dd + d] = v; d2t[d * Bsz + b] = v; }
        else     { d1[b * Dd + d] = v; }
    }
}

// Kernel 2: one block per (set, b): L2 norm of descriptor row.
__global__ __launch_bounds__(256) void norm_kernel(
    const float* __restrict__ d1, const float* __restrict__ d2,
    float* __restrict__ n1, float* __restrict__ n2)
{
    int b   = blockIdx.x & (Bsz - 1);
    int set = blockIdx.x >> 9;
    const float* dsc = set ? d2 : d1;
    float v = dsc[b * Dd + threadIdx.x];
    float s = waveSum(v * v);
    __shared__ float sh[4];
    int lane = threadIdx.x & 63, wv = threadIdx.x >> 6;
    if (lane == 0) sh[wv] = s;
    __syncthreads();
    if (threadIdx.x == 0) {
        float t = sh[0] + sh[1] + sh[2] + sh[3];
        (set ? n2 : n1)[b] = sqrtf(t);
    }
}

// Kernel 3: one block per row i. Each thread owns j = {2t, 2t+1} via float2
// loads of d2t; per-(i,j) FMA chain order unchanged (d ascending).
__global__ __launch_bounds__(256) void sim_kernel(
    const float* __restrict__ d1, const float* __restrict__ d2t,
    const float* __restrict__ n1, const float* __restrict__ n2,
    float* __restrict__ sim, float* __restrict__ pos, float* __restrict__ colmax)
{
    __shared__ float a[Dd];
    __shared__ float shm[4];
    int i = blockIdx.x, t = threadIdx.x;
    a[t] = d1[i * Dd + t];
    __syncthreads();
    const float2* __restrict__ D2 = (const float2*)d2t;
    float accx = 0.0f, accy = 0.0f;
    #pragma unroll 8
    for (int d = 0; d < Dd; ++d) {
        float ad = a[d];
        float2 v = D2[d * (Bsz / 2) + t];
        accx = fmaf(ad, v.x, accx);
        accy = fmaf(ad, v.y, accy);
    }
    int j0 = 2 * t, j1 = 2 * t + 1;
    float ni = n1[i];
    float2 nn = ((const float2*)n2)[t];
    float s0 = accx / fmaxf(ni * nn.x, EPS_COS);
    float s1 = accy / fmaxf(ni * nn.y, EPS_COS);
    float2 so; so.x = s0; so.y = s1;
    ((float2*)sim)[(size_t)i * (Bsz / 2) + t] = so;
    if (j0 == i) pos[i] = s0 / TEMP;
    if (j1 == i) pos[i] = s1 / TEMP;
    // max over all j (incl. diag) == max(pos, max offdiag); /T is monotone
    float m = waveMax(fmaxf(s0, s1));
    int lane = t & 63, wv = t >> 6;
    if (lane == 0) shm[wv] = m;
    __syncthreads();
    if (t == 0) {
        float mm = fmaxf(fmaxf(shm[0], shm[1]), fmaxf(shm[2], shm[3]));
        colmax[i] = mm / TEMP;
    }
}

// Kernel 4: one block per column j. row_max[j] (column max over i, excl diag,
// combined with pos[j]) and col_log[j] (uses colmax[j] from kernel 3).
__global__ __launch_bounds__(256) void col_kernel(
    const float* __restrict__ sim, const float* __restrict__ pos,
    const float* __restrict__ colmax,
    float* __restrict__ rowmax, float* __restrict__ collog)
{
    int j = blockIdx.x, t = threadIdx.x;
    int i0 = t, i1 = t + 256;
    float cm = colmax[j];
    float v0 = sim[(size_t)i0 * Bsz + j] / TEMP;
    float v1 = sim[(size_t)i1 * Bsz + j] / TEMP;
    bool ex0 = (i0 == j), ex1 = (i1 == j);
    float m  = fmaxf(ex0 ? -INFINITY : v0, ex1 ? -INFINITY : v1);
    float e  = (ex0 ? 0.0f : expf(v0 - cm)) + (ex1 ? 0.0f : expf(v1 - cm));
    m = waveMax(m);
    e = waveSum(e);
    __shared__ float shm[4], shs[4];
    int lane = t & 63, wv = t >> 6;
    if (lane == 0) { shm[wv] = m; shs[wv] = e; }
    __syncthreads();
    if (t == 0) {
        float mneg = fmaxf(fmaxf(shm[0], shm[1]), fmaxf(shm[2], shm[3]));
        float pj   = pos[j];
        rowmax[j]  = fmaxf(pj, mneg);
        float se   = shs[0] + shs[1] + shs[2] + shs[3];
        float cn   = expf(pj - cm);
        collog[j]  = logf(cn / (se + cn) + EPS_LOG);
    }
}

// Kernel 5: one block per row i. row_den uses row_max[j] per column.
__global__ __launch_bounds__(256) void row_kernel(
    const float* __restrict__ sim, const float* __restrict__ pos,
    const float* __restrict__ rowmax, const float* __restrict__ collog,
    float* __restrict__ part)
{
    int i = blockIdx.x, t = threadIdx.x;
    int j0 = t, j1 = t + 256;
    float s0 = sim[(size_t)i * Bsz + j0];
    float s1 = sim[(size_t)i * Bsz + j1];
    float r0 = rowmax[j0];
    float r1 = rowmax[j1];
    float e = 0.0f;
    if (j0 != i) e += expf(s0 / TEMP - r0);
    if (j1 != i) e += expf(s1 / TEMP - r1);
    e = waveSum(e);
    __shared__ float shs[4];
    int lane = t & 63, wv = t >> 6;
    if (lane == 0) shs[wv] = e;
    __syncthreads();
    if (t == 0) {
        float se = shs[0] + shs[1] + shs[2] + shs[3];
        float rn = expf(pos[i] - rowmax[i]);
        float rl = logf(rn / (se + rn) + EPS_LOG);
        part[i] = -rl - collog[i];
    }
}

// Kernel 6: final reduce of 512 partials.
__global__ __launch_bounds__(256) void final_kernel(
    const float* __restrict__ part, float* __restrict__ out)
{
    int t = threadIdx.x;
    float s = part[t] + part[t + 256];
    s = waveSum(s);
    __shared__ float shs[4];
    int lane = t & 63, wv = t >> 6;
    if (lane == 0) shs[wv] = s;
    __syncthreads();
    if (t == 0) out[0] = (shs[0] + shs[1] + shs[2] + shs[3]) * (1.0f / (2.0f * Bsz));
}

extern "C" void kernel_launch(void* const* d_in, const int* in_sizes, int n_in,
                              void* d_out, int out_size, void* d_ws, size_t ws_size,
                              hipStream_t stream) {
    const float* f1  = (const float*)d_in[0];
    const float* f2  = (const float*)d_in[1];
    const float* bb1 = (const float*)d_in[2];
    const float* bb2 = (const float*)d_in[3];
    float* out = (float*)d_out;

    float* ws = (float*)d_ws;
    float* d1     = ws;                       // B*D
    float* d2     = d1  + Bsz * Dd;           // B*D
    float* d2t    = d2  + Bsz * Dd;           // D*B
    float* sim    = d2t + Dd * Bsz;           // B*B
    float* n1     = sim + (size_t)Bsz * Bsz;  // B
    float* n2     = n1 + Bsz;
    float* pos    = n2 + Bsz;
    float* colmax = pos + Bsz;
    float* rowmax = colmax + Bsz;
    float* collog = rowmax + Bsz;
    float* part   = collog + Bsz;

    // K1: 2*B*D waves, 4 waves/block
    desc_kernel<<<(2 * Bsz * Dd) / 4, 256, 0, stream>>>(f1, f2, bb1, bb2, d1, d2, d2t);
    norm_kernel<<<2 * Bsz, 256, 0, stream>>>(d1, d2, n1, n2);
    sim_kernel<<<Bsz, 256, 0, stream>>>(d1, d2t, n1, n2, sim, pos, colmax);
    col_kernel<<<Bsz, 256, 0, stream>>>(sim, pos, colmax, rowmax, collog);
    row_kernel<<<Bsz, 256, 0, stream>>>(sim, pos, rowmax, collog, part);
    final_kernel<<<1, 256, 0, stream>>>(part, out);
}